// Round 8
// baseline (202.501 us; speedup 1.0000x reference)
//
#include <hip/hip_runtime.h>

#define HW 65536
#define NBATCH 16
#define CCH 64
#define QKC 32

// workspace layout (float offsets)
#define OFF_WQT 0        // [64][32]  WqT folded (c-major rows of 32)
#define OFF_BQ  2048     // [32]
#define OFF_WKT 2080     // [64][32]
#define OFF_BK  4128     // [32]
#define OFF_WVT 4160     // [64][64]
#define OFF_BV  8256     // [64]
#define OFF_WO  8320     // [64][64]  row-major [c][j]
#define OFF_BO  12416    // [64]
#define OFF_F   12544    // [16][32][64]
#define OFF_MT  45312    // [16][32][64]
#define OFF_STAGE 81920  // bf16 x-stage: [n*4096+g][64 lanes][16 shorts] = 134 MB
#define STAGE_BYTES_NEEDED (81920ull * 4ull + (unsigned long long)NBATCH * 4096ull * 2048ull)

#define BPN_A 128
#define BPN_B 128
#define NIT_A ((HW / 64) / BPN_A)   // 8 chunks per block, pass A
#define NIT_B ((HW / 64) / BPN_B)   // 8 chunks per block, pass B

typedef __attribute__((ext_vector_type(4))) float f32x4;
typedef __attribute__((ext_vector_type(8))) short bf16x8;
typedef __attribute__((ext_vector_type(4))) short bf16x4;

#define MFMA_P(a, b, c) __builtin_amdgcn_mfma_f32_16x16x32_bf16(a, b, c, 0, 0, 0)
#define MFMA_O(a, b, c) __builtin_amdgcn_mfma_f32_16x16x16bf16_1k(a, b, c, 0, 0, 0)

// float -> bf16 via hardware cvt (m240: plain cast compiles to the HW instr)
__device__ __forceinline__ short f2bf(float f) {
    __bf16 h = (__bf16)f;
    return __builtin_bit_cast(short, h);
}

__global__ __launch_bounds__(256) void k0_fold(
    const float* __restrict__ Wq, const float* __restrict__ bq,
    const float* __restrict__ qg, const float* __restrict__ qb,
    const float* __restrict__ qm, const float* __restrict__ qv,
    const float* __restrict__ Wk, const float* __restrict__ bk,
    const float* __restrict__ kg, const float* __restrict__ kb,
    const float* __restrict__ km, const float* __restrict__ kvar,
    const float* __restrict__ Wv, const float* __restrict__ bv,
    const float* __restrict__ vg, const float* __restrict__ vb,
    const float* __restrict__ vm, const float* __restrict__ vvar,
    const float* __restrict__ Wo, const float* __restrict__ bo,
    const float* __restrict__ og, const float* __restrict__ ob,
    const float* __restrict__ om, const float* __restrict__ ovar,
    float* __restrict__ ws)
{
    const int idx = blockIdx.x * 256 + threadIdx.x;
    if (idx < 2048) {                       // WqT[c][i]
        const int c = idx >> 5, i = idx & 31;
        const float s = qg[i] * rsqrtf(qv[i] + 1e-5f);
        ws[OFF_WQT + idx] = Wq[i * 64 + c] * s;
    } else if (idx < 2080) {
        const int i = idx - 2048;
        const float s = qg[i] * rsqrtf(qv[i] + 1e-5f);
        ws[OFF_BQ + i] = bq[i] * s + qb[i] - qm[i] * s;
    } else if (idx < 4128) {                // WkT[c][i]
        const int t = idx - 2080;
        const int c = t >> 5, i = t & 31;
        const float s = kg[i] * rsqrtf(kvar[i] + 1e-5f);
        ws[OFF_WKT + t] = Wk[i * 64 + c] * s;
    } else if (idx < 4160) {
        const int i = idx - 4128;
        const float s = kg[i] * rsqrtf(kvar[i] + 1e-5f);
        ws[OFF_BK + i] = bk[i] * s + kb[i] - km[i] * s;
    } else if (idx < 8256) {                // WvT[c][o]
        const int t = idx - 4160;
        const int c = t >> 6, o = t & 63;
        const float s = vg[o] * rsqrtf(vvar[o] + 1e-5f);
        ws[OFF_WVT + t] = Wv[o * 64 + c] * s;
    } else if (idx < 8320) {
        const int o = idx - 8256;
        const float s = vg[o] * rsqrtf(vvar[o] + 1e-5f);
        ws[OFF_BV + o] = bv[o] * s + vb[o] - vm[o] * s;
    } else if (idx < 12416) {               // Wo'[c][j]
        const int t = idx - 8320;
        const int c = t >> 6, j = t & 63;
        const float s = og[c] * rsqrtf(ovar[c] + 1e-5f);
        ws[OFF_WO + t] = Wo[c * 64 + j] * s;
    } else if (idx < 12480) {
        const int c = idx - 12416;
        const float s = og[c] * rsqrtf(ovar[c] + 1e-5f);
        ws[OFF_BO + c] = bo[c] * s + ob[c] - om[c] * s;
    } else if (idx < 12480 + 32768) {       // zero F (must happen every launch)
        ws[OFF_F + (idx - 12480)] = 0.0f;
    }
}

// Pass A (MFMA): per wave, 16-pixel groups, ascending chunks, x double-buffered.
// STAGE=true additionally writes each lane's bf16 A-fragments (32 B) to the
// stage buffer in exactly the layout pass B consumes -> pass B never touches
// fp32 x and does zero conversions.
template <bool STAGE>
__global__ __launch_bounds__(256) void k1_passA(const float* __restrict__ x,
                                                const float* __restrict__ wsc,
                                                float* __restrict__ f,
                                                short* __restrict__ stage)
{
    __shared__ float red[4 * 2048];

    const int tid = threadIdx.x;
    const int w = tid >> 6;
    const int lane = tid & 63;
    const int ln = lane & 15;
    const int lg = lane >> 4;

    const int n = blockIdx.x / BPN_A;
    const int bslot = blockIdx.x % BPN_A;
    const float* xn = x + (size_t)n * CCH * HW;

    bf16x8 wkf[2][2];
#pragma unroll
    for (int kk = 0; kk < 2; kk++)
#pragma unroll
        for (int t = 0; t < 2; t++) {
            bf16x8 a;
#pragma unroll
            for (int j = 0; j < 8; j++)
                a[j] = f2bf(wsc[OFF_WKT + (kk * 32 + lg * 8 + j) * 32 + t * 16 + ln]);
            wkf[kk][t] = a;
        }
    bf16x8 wvf[2][4];
#pragma unroll
    for (int kk = 0; kk < 2; kk++)
#pragma unroll
        for (int t = 0; t < 4; t++) {
            bf16x8 a;
#pragma unroll
            for (int j = 0; j < 8; j++)
                a[j] = f2bf(wsc[OFF_WVT + (kk * 32 + lg * 8 + j) * 64 + t * 16 + ln]);
            wvf[kk][t] = a;
        }
    float bkb[2], bvb[4];
#pragma unroll
    for (int t = 0; t < 2; t++) bkb[t] = wsc[OFF_BK + t * 16 + ln];
#pragma unroll
    for (int t = 0; t < 4; t++) bvb[t] = wsc[OFF_BV + t * 16 + ln];

    f32x4 facc[2][4];
#pragma unroll
    for (int t = 0; t < 2; t++)
#pragma unroll
        for (int vt = 0; vt < 4; vt++) facc[t][vt] = (f32x4){0.f, 0.f, 0.f, 0.f};

    float xf[16];
    {
        const int sbase = bslot * 64 + w * 16;
#pragma unroll
        for (int kk = 0; kk < 2; kk++) {
            const float* xp = xn + (size_t)(kk * 32 + lg * 8) * HW + sbase + ln;
#pragma unroll
            for (int j = 0; j < 8; j++) xf[kk * 8 + j] = xp[j * HW];
        }
    }

#pragma unroll
    for (int it = 0; it < NIT_A; ++it) {
        const int sbase = (bslot + it * BPN_A) * 64 + w * 16;

        float xf2[16];
        if (it + 1 < NIT_A) {
            const int sb2 = (bslot + (it + 1) * BPN_A) * 64 + w * 16;
#pragma unroll
            for (int kk = 0; kk < 2; kk++) {
                const float* xp = xn + (size_t)(kk * 32 + lg * 8) * HW + sb2 + ln;
#pragma unroll
                for (int j = 0; j < 8; j++) xf2[kk * 8 + j] = xp[j * HW];
            }
        }

        bf16x8 xa[2];
#pragma unroll
        for (int kk = 0; kk < 2; kk++)
#pragma unroll
            for (int j = 0; j < 8; j++) xa[kk][j] = f2bf(xf[kk * 8 + j]);

        if (STAGE) {
            // group id g = n*4096 + sbase/16; lane's 16 shorts contiguous
            short* sp = stage + ((size_t)n * 4096 + (sbase >> 4)) * 1024 + lane * 16;
            *(bf16x8*)sp = xa[0];
            *(bf16x8*)(sp + 8) = xa[1];
        }

        f32x4 dk[2], dv[4];
#pragma unroll
        for (int t = 0; t < 2; t++) dk[t] = (f32x4){bkb[t], bkb[t], bkb[t], bkb[t]};
#pragma unroll
        for (int t = 0; t < 4; t++) dv[t] = (f32x4){bvb[t], bvb[t], bvb[t], bvb[t]};
#pragma unroll
        for (int kk = 0; kk < 2; kk++) {
#pragma unroll
            for (int t = 0; t < 2; t++) dk[t] = MFMA_P(xa[kk], wkf[kk][t], dk[t]);
#pragma unroll
            for (int t = 0; t < 4; t++) dv[t] = MFMA_P(xa[kk], wvf[kk][t], dv[t]);
        }

        float inv[4];
#pragma unroll
        for (int r = 0; r < 4; r++) {
            float s = dk[0][r] * dk[0][r] + dk[1][r] * dk[1][r];
            s += __shfl_xor(s, 1, 64);
            s += __shfl_xor(s, 2, 64);
            s += __shfl_xor(s, 4, 64);
            s += __shfl_xor(s, 8, 64);
            inv[r] = 1.0f / fmaxf(sqrtf(s), 1e-12f);
        }

        bf16x4 ka[2], vb[4];
#pragma unroll
        for (int t = 0; t < 2; t++)
#pragma unroll
            for (int r = 0; r < 4; r++) ka[t][r] = f2bf(dk[t][r] * inv[r]);
#pragma unroll
        for (int t = 0; t < 4; t++)
#pragma unroll
            for (int r = 0; r < 4; r++) vb[t][r] = f2bf(fmaxf(dv[t][r], 0.0f));

#pragma unroll
        for (int t = 0; t < 2; t++)
#pragma unroll
            for (int vt = 0; vt < 4; vt++)
                facc[t][vt] = MFMA_O(ka[t], vb[vt], facc[t][vt]);

        if (it + 1 < NIT_A) {
#pragma unroll
            for (int i = 0; i < 16; i++) xf[i] = xf2[i];
        }
    }

#pragma unroll
    for (int t = 0; t < 2; t++)
#pragma unroll
        for (int vt = 0; vt < 4; vt++)
#pragma unroll
            for (int r = 0; r < 4; r++)
                red[w * 2048 + (t * 16 + lg * 4 + r) * 64 + vt * 16 + ln] = facc[t][vt][r];
    __syncthreads();
    float* fn = f + n * (QKC * CCH);
    for (int idx = tid; idx < 2048; idx += 256)
        atomicAdd(&fn[idx], red[idx] + red[2048 + idx] + red[4096 + idx] + red[6144 + idx]);
}

// MT[n][i][c] = sum_j Wo'[c][j] * F[n][i][j]
__global__ __launch_bounds__(256) void k2_M(const float* __restrict__ wsc,
                                            float* __restrict__ ws)
{
    const int idx = blockIdx.x * 256 + threadIdx.x;
    if (idx >= NBATCH * QKC * CCH) return;
    const int n = idx / (QKC * CCH);
    const int r = idx % (QKC * CCH);
    const int i = r >> 6, c = r & 63;
    const float* wo = wsc + OFF_WO + c * 64;
    const float* fr = wsc + OFF_F + n * 2048 + i * 64;
    float acc = 0.0f;
#pragma unroll
    for (int j = 0; j < 64; j++) acc += wo[j] * fr[j];
    ws[OFF_MT + idx] = acc;
}

// Shared tail of pass B: given xa frags, compute q̂, y, v0; store out.
__device__ __forceinline__ void passB_body(
    const bf16x8 xa[2], const bf16x8 wqf[2][2], const bf16x8 wvf[2][4],
    const bf16x8 mtf[4], const float bqb[2], const float bvb[4],
    const float bob[4], float* qtw, float* on, int sbase,
    int ln, int lg)
{
    f32x4 dq[2], dv0[4];
#pragma unroll
    for (int t = 0; t < 2; t++) dq[t] = (f32x4){bqb[t], bqb[t], bqb[t], bqb[t]};
#pragma unroll
    for (int t = 0; t < 4; t++) dv0[t] = (f32x4){bvb[t], bvb[t], bvb[t], bvb[t]};
#pragma unroll
    for (int kk = 0; kk < 2; kk++) {
#pragma unroll
        for (int t = 0; t < 2; t++) dq[t] = MFMA_P(xa[kk], wqf[kk][t], dq[t]);
#pragma unroll
        for (int t = 0; t < 4; t++) dv0[t] = MFMA_P(xa[kk], wvf[kk][t], dv0[t]);
    }

    float inv[4];
#pragma unroll
    for (int r = 0; r < 4; r++) {
        float s = dq[0][r] * dq[0][r] + dq[1][r] * dq[1][r];
        s += __shfl_xor(s, 1, 64);
        s += __shfl_xor(s, 2, 64);
        s += __shfl_xor(s, 4, 64);
        s += __shfl_xor(s, 8, 64);
        inv[r] = 1.0f / fmaxf(sqrtf(s), 1e-12f);
    }

    // transpose q̂ through the wave-private LDS slab (wave-local ordering only)
#pragma unroll
    for (int t = 0; t < 2; t++)
#pragma unroll
        for (int r = 0; r < 4; r++)
            qtw[(lg * 4 + r) * 36 + t * 16 + ln] = dq[t][r] * inv[r];
    const f32x4 qlo = *(const f32x4*)&qtw[ln * 36 + lg * 8];
    const f32x4 qhi = *(const f32x4*)&qtw[ln * 36 + lg * 8 + 4];
    bf16x8 aq;
#pragma unroll
    for (int j = 0; j < 4; j++) { aq[j] = f2bf(qlo[j]); aq[4 + j] = f2bf(qhi[j]); }

    f32x4 dy[4];
#pragma unroll
    for (int t = 0; t < 4; t++) dy[t] = (f32x4){bob[t], bob[t], bob[t], bob[t]};
#pragma unroll
    for (int t = 0; t < 4; t++) dy[t] = MFMA_P(aq, mtf[t], dy[t]);

#pragma unroll
    for (int t = 0; t < 4; t++) {
        float* op = on + (size_t)(t * 16 + ln) * HW + sbase + lg * 4;
        f32x4 o4;
#pragma unroll
        for (int r = 0; r < 4; r++)
            o4[r] = fmaxf(dy[t][r], 0.0f) + dv0[t][r];
        __builtin_nontemporal_store(o4, (f32x4*)op);
    }
}

__device__ __forceinline__ void passB_loadw(
    const float* wsc, int n, int ln, int lg,
    bf16x8 wqf[2][2], bf16x8 wvf[2][4], bf16x8 mtf[4],
    float bqb[2], float bvb[4], float bob[4])
{
#pragma unroll
    for (int kk = 0; kk < 2; kk++)
#pragma unroll
        for (int t = 0; t < 2; t++) {
            bf16x8 a;
#pragma unroll
            for (int j = 0; j < 8; j++)
                a[j] = f2bf(wsc[OFF_WQT + (kk * 32 + lg * 8 + j) * 32 + t * 16 + ln]);
            wqf[kk][t] = a;
        }
#pragma unroll
    for (int kk = 0; kk < 2; kk++)
#pragma unroll
        for (int t = 0; t < 4; t++) {
            bf16x8 a;
#pragma unroll
            for (int j = 0; j < 8; j++)
                a[j] = f2bf(wsc[OFF_WVT + (kk * 32 + lg * 8 + j) * 64 + t * 16 + ln]);
            wvf[kk][t] = a;
        }
#pragma unroll
    for (int t = 0; t < 4; t++) {
        bf16x8 a;
#pragma unroll
        for (int j = 0; j < 8; j++)
            a[j] = f2bf(wsc[OFF_MT + n * 2048 + (lg * 8 + j) * 64 + t * 16 + ln]);
        mtf[t] = a;
    }
#pragma unroll
    for (int t = 0; t < 2; t++) bqb[t] = wsc[OFF_BQ + t * 16 + ln];
#pragma unroll
    for (int t = 0; t < 4; t++) bvb[t] = wsc[OFF_BV + t * 16 + ln];
#pragma unroll
    for (int t = 0; t < 4; t++) bob[t] = wsc[OFF_BO + t * 16 + ln];
}

// Pass B staged: reads bf16 fragments from the L3-resident stage buffer
// (2 contiguous 16B loads/lane vs 16 strided dwords), zero conversions.
__global__ __launch_bounds__(256) void k3_passB_staged(const short* __restrict__ stage,
                                                       const float* __restrict__ wsc,
                                                       float* __restrict__ out)
{
    __shared__ float qt[4][16 * 36];

    const int tid = threadIdx.x;
    const int w = tid >> 6;
    const int lane = tid & 63;
    const int ln = lane & 15;
    const int lg = lane >> 4;

    const int n = blockIdx.x / BPN_B;
    const int slot = blockIdx.x % BPN_B;
    float* on = out + (size_t)n * CCH * HW;

    bf16x8 wqf[2][2], wvf[2][4], mtf[4];
    float bqb[2], bvb[4], bob[4];
    passB_loadw(wsc, n, ln, lg, wqf, wvf, mtf, bqb, bvb, bob);

    const int c0 = (HW / 64) - 1 - slot;   // descending: consume k1's tail first

    bf16x8 xa[2];
    {
        const short* sp = stage + ((size_t)n * 4096 + ((c0 * 64 + w * 16) >> 4)) * 1024 + lane * 16;
        xa[0] = *(const bf16x8*)sp;
        xa[1] = *(const bf16x8*)(sp + 8);
    }

#pragma unroll
    for (int it = 0; it < NIT_B; ++it) {
        const int sbase = (c0 - it * BPN_B) * 64 + w * 16;

        bf16x8 xn2[2];
        if (it + 1 < NIT_B) {
            const int sb2 = (c0 - (it + 1) * BPN_B) * 64 + w * 16;
            const short* sp = stage + ((size_t)n * 4096 + (sb2 >> 4)) * 1024 + lane * 16;
            xn2[0] = *(const bf16x8*)sp;
            xn2[1] = *(const bf16x8*)(sp + 8);
        }

        passB_body(xa, wqf, wvf, mtf, bqb, bvb, bob, qt[w], on, sbase, ln, lg);

        if (it + 1 < NIT_B) { xa[0] = xn2[0]; xa[1] = xn2[1]; }
    }
}

// Pass B direct (fallback when ws is too small for the stage buffer).
__global__ __launch_bounds__(256) void k3_passB_direct(const float* __restrict__ x,
                                                       const float* __restrict__ wsc,
                                                       float* __restrict__ out)
{
    __shared__ float qt[4][16 * 36];

    const int tid = threadIdx.x;
    const int w = tid >> 6;
    const int lane = tid & 63;
    const int ln = lane & 15;
    const int lg = lane >> 4;

    const int n = blockIdx.x / BPN_B;
    const int slot = blockIdx.x % BPN_B;
    const float* xn = x + (size_t)n * CCH * HW;
    float* on = out + (size_t)n * CCH * HW;

    bf16x8 wqf[2][2], wvf[2][4], mtf[4];
    float bqb[2], bvb[4], bob[4];
    passB_loadw(wsc, n, ln, lg, wqf, wvf, mtf, bqb, bvb, bob);

    const int c0 = (HW / 64) - 1 - slot;

    float xf[16];
    {
        const int sbase = c0 * 64 + w * 16;
#pragma unroll
        for (int kk = 0; kk < 2; kk++) {
            const float* xp = xn + (size_t)(kk * 32 + lg * 8) * HW + sbase + ln;
#pragma unroll
            for (int j = 0; j < 8; j++) xf[kk * 8 + j] = xp[j * HW];
        }
    }

#pragma unroll
    for (int it = 0; it < NIT_B; ++it) {
        const int sbase = (c0 - it * BPN_B) * 64 + w * 16;

        float xf2[16];
        if (it + 1 < NIT_B) {
            const int sb2 = (c0 - (it + 1) * BPN_B) * 64 + w * 16;
#pragma unroll
            for (int kk = 0; kk < 2; kk++) {
                const float* xp = xn + (size_t)(kk * 32 + lg * 8) * HW + sb2 + ln;
#pragma unroll
                for (int j = 0; j < 8; j++) xf2[kk * 8 + j] = xp[j * HW];
            }
        }

        bf16x8 xa[2];
#pragma unroll
        for (int kk = 0; kk < 2; kk++)
#pragma unroll
            for (int j = 0; j < 8; j++) xa[kk][j] = f2bf(xf[kk * 8 + j]);

        passB_body(xa, wqf, wvf, mtf, bqb, bvb, bob, qt[w], on, sbase, ln, lg);

        if (it + 1 < NIT_B) {
#pragma unroll
            for (int i = 0; i < 16; i++) xf[i] = xf2[i];
        }
    }
}

extern "C" void kernel_launch(void* const* d_in, const int* in_sizes, int n_in,
                              void* d_out, int out_size, void* d_ws, size_t ws_size,
                              hipStream_t stream)
{
    const float* x    = (const float*)d_in[0];
    const float* Wq   = (const float*)d_in[1];
    const float* bq   = (const float*)d_in[2];
    const float* qg   = (const float*)d_in[3];
    const float* qb   = (const float*)d_in[4];
    const float* qm   = (const float*)d_in[5];
    const float* qv   = (const float*)d_in[6];
    const float* Wk   = (const float*)d_in[7];
    const float* bk   = (const float*)d_in[8];
    const float* kg   = (const float*)d_in[9];
    const float* kb   = (const float*)d_in[10];
    const float* km   = (const float*)d_in[11];
    const float* kvar = (const float*)d_in[12];
    const float* Wv   = (const float*)d_in[13];
    const float* bv   = (const float*)d_in[14];
    const float* vg   = (const float*)d_in[15];
    const float* vb   = (const float*)d_in[16];
    const float* vm   = (const float*)d_in[17];
    const float* vvar = (const float*)d_in[18];
    const float* Wo   = (const float*)d_in[19];
    const float* bo   = (const float*)d_in[20];
    const float* og   = (const float*)d_in[21];
    const float* ob   = (const float*)d_in[22];
    const float* om   = (const float*)d_in[23];
    const float* ovar = (const float*)d_in[24];

    float* ws  = (float*)d_ws;
    float* out = (float*)d_out;
    short* stage = (short*)(ws + OFF_STAGE);
    const bool use_stage = (ws_size >= STAGE_BYTES_NEEDED);

    k0_fold<<<177, 256, 0, stream>>>(Wq, bq, qg, qb, qm, qv,
                                     Wk, bk, kg, kb, km, kvar,
                                     Wv, bv, vg, vb, vm, vvar,
                                     Wo, bo, og, ob, om, ovar, ws);

    if (use_stage) {
        k1_passA<true><<<NBATCH * BPN_A, 256, 0, stream>>>(x, (const float*)ws,
                                                           ws + OFF_F, stage);
        k2_M<<<128, 256, 0, stream>>>((const float*)ws, ws);
        k3_passB_staged<<<NBATCH * BPN_B, 256, 0, stream>>>((const short*)stage,
                                                            (const float*)ws, out);
    } else {
        k1_passA<false><<<NBATCH * BPN_A, 256, 0, stream>>>(x, (const float*)ws,
                                                            ws + OFF_F, stage);
        k2_M<<<128, 256, 0, stream>>>((const float*)ws, ws);
        k3_passB_direct<<<NBATCH * BPN_B, 256, 0, stream>>>(x, (const float*)ws, out);
    }
}

// Round 9
// 185.061 us; speedup vs baseline: 1.0942x; 1.0942x over previous
//
#include <hip/hip_runtime.h>

#define HW 65536
#define NBATCH 16
#define CCH 64
#define QKC 32

// workspace layout (float offsets)
#define OFF_WQT 0        // [64][32]  WqT folded (c-major rows of 32)
#define OFF_BQ  2048     // [32]
#define OFF_WKT 2080     // [64][32]
#define OFF_BK  4128     // [32]
#define OFF_WVT 4160     // [64][64]
#define OFF_BV  8256     // [64]
#define OFF_WO  8320     // [64][64]  row-major [c][j]
#define OFF_BO  12416    // [64]
#define OFF_F   12544    // [16][32][64]
#define OFF_MT  45312    // [16][32][64]

#define BPN_A 128
#define BPN_B 128
#define NIT_A ((HW / 64) / BPN_A)   // 8 chunks (one contiguous 512-px span) per block
#define NIT_B ((HW / 64) / BPN_B)

typedef __attribute__((ext_vector_type(4))) float f32x4;
typedef __attribute__((ext_vector_type(8))) short bf16x8;
typedef __attribute__((ext_vector_type(4))) short bf16x4;

#define MFMA_P(a, b, c) __builtin_amdgcn_mfma_f32_16x16x32_bf16(a, b, c, 0, 0, 0)
#define MFMA_O(a, b, c) __builtin_amdgcn_mfma_f32_16x16x16bf16_1k(a, b, c, 0, 0, 0)

// float -> bf16 via hardware cvt (m240: plain cast compiles to the HW instr)
__device__ __forceinline__ short f2bf(float f) {
    __bf16 h = (__bf16)f;
    return __builtin_bit_cast(short, h);
}

__global__ __launch_bounds__(256) void k0_fold(
    const float* __restrict__ Wq, const float* __restrict__ bq,
    const float* __restrict__ qg, const float* __restrict__ qb,
    const float* __restrict__ qm, const float* __restrict__ qv,
    const float* __restrict__ Wk, const float* __restrict__ bk,
    const float* __restrict__ kg, const float* __restrict__ kb,
    const float* __restrict__ km, const float* __restrict__ kvar,
    const float* __restrict__ Wv, const float* __restrict__ bv,
    const float* __restrict__ vg, const float* __restrict__ vb,
    const float* __restrict__ vm, const float* __restrict__ vvar,
    const float* __restrict__ Wo, const float* __restrict__ bo,
    const float* __restrict__ og, const float* __restrict__ ob,
    const float* __restrict__ om, const float* __restrict__ ovar,
    float* __restrict__ ws)
{
    const int idx = blockIdx.x * 256 + threadIdx.x;
    if (idx < 2048) {                       // WqT[c][i]
        const int c = idx >> 5, i = idx & 31;
        const float s = qg[i] * rsqrtf(qv[i] + 1e-5f);
        ws[OFF_WQT + idx] = Wq[i * 64 + c] * s;
    } else if (idx < 2080) {
        const int i = idx - 2048;
        const float s = qg[i] * rsqrtf(qv[i] + 1e-5f);
        ws[OFF_BQ + i] = bq[i] * s + qb[i] - qm[i] * s;
    } else if (idx < 4128) {                // WkT[c][i]
        const int t = idx - 2080;
        const int c = t >> 5, i = t & 31;
        const float s = kg[i] * rsqrtf(kvar[i] + 1e-5f);
        ws[OFF_WKT + t] = Wk[i * 64 + c] * s;
    } else if (idx < 4160) {
        const int i = idx - 4128;
        const float s = kg[i] * rsqrtf(kvar[i] + 1e-5f);
        ws[OFF_BK + i] = bk[i] * s + kb[i] - km[i] * s;
    } else if (idx < 8256) {                // WvT[c][o]
        const int t = idx - 4160;
        const int c = t >> 6, o = t & 63;
        const float s = vg[o] * rsqrtf(vvar[o] + 1e-5f);
        ws[OFF_WVT + t] = Wv[o * 64 + c] * s;
    } else if (idx < 8320) {
        const int o = idx - 8256;
        const float s = vg[o] * rsqrtf(vvar[o] + 1e-5f);
        ws[OFF_BV + o] = bv[o] * s + vb[o] - vm[o] * s;
    } else if (idx < 12416) {               // Wo'[c][j]
        const int t = idx - 8320;
        const int c = t >> 6, j = t & 63;
        const float s = og[c] * rsqrtf(ovar[c] + 1e-5f);
        ws[OFF_WO + t] = Wo[c * 64 + j] * s;
    } else if (idx < 12480) {
        const int c = idx - 12416;
        const float s = og[c] * rsqrtf(ovar[c] + 1e-5f);
        ws[OFF_BO + c] = bo[c] * s + ob[c] - om[c] * s;
    } else if (idx < 12480 + 32768) {       // zero F (must happen every launch)
        ws[OFF_F + (idx - 12480)] = 0.0f;
    }
}

// Pass A (MFMA): each block owns a CONTIGUOUS 512-px span per channel
// (DRAM row-buffer friendly: 2 KB contiguous per channel per block, vs the
// previous 8192-px-strided chunk walk). x double-buffered in fp32 regs.
__global__ __launch_bounds__(256) void k1_passA(const float* __restrict__ x,
                                                const float* __restrict__ wsc,
                                                float* __restrict__ f)
{
    __shared__ float red[4 * 2048];

    const int tid = threadIdx.x;
    const int w = tid >> 6;
    const int lane = tid & 63;
    const int ln = lane & 15;
    const int lg = lane >> 4;

    const int n = blockIdx.x / BPN_A;
    const int bslot = blockIdx.x % BPN_A;
    const float* xn = x + (size_t)n * CCH * HW;

    bf16x8 wkf[2][2];
#pragma unroll
    for (int kk = 0; kk < 2; kk++)
#pragma unroll
        for (int t = 0; t < 2; t++) {
            bf16x8 a;
#pragma unroll
            for (int j = 0; j < 8; j++)
                a[j] = f2bf(wsc[OFF_WKT + (kk * 32 + lg * 8 + j) * 32 + t * 16 + ln]);
            wkf[kk][t] = a;
        }
    bf16x8 wvf[2][4];
#pragma unroll
    for (int kk = 0; kk < 2; kk++)
#pragma unroll
        for (int t = 0; t < 4; t++) {
            bf16x8 a;
#pragma unroll
            for (int j = 0; j < 8; j++)
                a[j] = f2bf(wsc[OFF_WVT + (kk * 32 + lg * 8 + j) * 64 + t * 16 + ln]);
            wvf[kk][t] = a;
        }
    float bkb[2], bvb[4];
#pragma unroll
    for (int t = 0; t < 2; t++) bkb[t] = wsc[OFF_BK + t * 16 + ln];
#pragma unroll
    for (int t = 0; t < 4; t++) bvb[t] = wsc[OFF_BV + t * 16 + ln];

    f32x4 facc[2][4];
#pragma unroll
    for (int t = 0; t < 2; t++)
#pragma unroll
        for (int vt = 0; vt < 4; vt++) facc[t][vt] = (f32x4){0.f, 0.f, 0.f, 0.f};

    const int span0 = bslot * NIT_A;   // contiguous span: chunks span0..span0+7

    float xf[16];
    {
        const int sbase = span0 * 64 + w * 16;
#pragma unroll
        for (int kk = 0; kk < 2; kk++) {
            const float* xp = xn + (size_t)(kk * 32 + lg * 8) * HW + sbase + ln;
#pragma unroll
            for (int j = 0; j < 8; j++) xf[kk * 8 + j] = xp[j * HW];
        }
    }

#pragma unroll
    for (int it = 0; it < NIT_A; ++it) {
        float xf2[16];
        if (it + 1 < NIT_A) {
            const int sb2 = (span0 + it + 1) * 64 + w * 16;
#pragma unroll
            for (int kk = 0; kk < 2; kk++) {
                const float* xp = xn + (size_t)(kk * 32 + lg * 8) * HW + sb2 + ln;
#pragma unroll
                for (int j = 0; j < 8; j++) xf2[kk * 8 + j] = xp[j * HW];
            }
        }

        bf16x8 xa[2];
#pragma unroll
        for (int kk = 0; kk < 2; kk++)
#pragma unroll
            for (int j = 0; j < 8; j++) xa[kk][j] = f2bf(xf[kk * 8 + j]);

        f32x4 dk[2], dv[4];
#pragma unroll
        for (int t = 0; t < 2; t++) dk[t] = (f32x4){bkb[t], bkb[t], bkb[t], bkb[t]};
#pragma unroll
        for (int t = 0; t < 4; t++) dv[t] = (f32x4){bvb[t], bvb[t], bvb[t], bvb[t]};
#pragma unroll
        for (int kk = 0; kk < 2; kk++) {
#pragma unroll
            for (int t = 0; t < 2; t++) dk[t] = MFMA_P(xa[kk], wkf[kk][t], dk[t]);
#pragma unroll
            for (int t = 0; t < 4; t++) dv[t] = MFMA_P(xa[kk], wvf[kk][t], dv[t]);
        }

        float inv[4];
#pragma unroll
        for (int r = 0; r < 4; r++) {
            float s = dk[0][r] * dk[0][r] + dk[1][r] * dk[1][r];
            s += __shfl_xor(s, 1, 64);
            s += __shfl_xor(s, 2, 64);
            s += __shfl_xor(s, 4, 64);
            s += __shfl_xor(s, 8, 64);
            inv[r] = 1.0f / fmaxf(sqrtf(s), 1e-12f);
        }

        bf16x4 ka[2], vb[4];
#pragma unroll
        for (int t = 0; t < 2; t++)
#pragma unroll
            for (int r = 0; r < 4; r++) ka[t][r] = f2bf(dk[t][r] * inv[r]);
#pragma unroll
        for (int t = 0; t < 4; t++)
#pragma unroll
            for (int r = 0; r < 4; r++) vb[t][r] = f2bf(fmaxf(dv[t][r], 0.0f));

#pragma unroll
        for (int t = 0; t < 2; t++)
#pragma unroll
            for (int vt = 0; vt < 4; vt++)
                facc[t][vt] = MFMA_O(ka[t], vb[vt], facc[t][vt]);

        if (it + 1 < NIT_A) {
#pragma unroll
            for (int i = 0; i < 16; i++) xf[i] = xf2[i];
        }
    }

#pragma unroll
    for (int t = 0; t < 2; t++)
#pragma unroll
        for (int vt = 0; vt < 4; vt++)
#pragma unroll
            for (int r = 0; r < 4; r++)
                red[w * 2048 + (t * 16 + lg * 4 + r) * 64 + vt * 16 + ln] = facc[t][vt][r];
    __syncthreads();
    float* fn = f + n * (QKC * CCH);
    for (int idx = tid; idx < 2048; idx += 256)
        atomicAdd(&fn[idx], red[idx] + red[2048 + idx] + red[4096 + idx] + red[6144 + idx]);
}

// MT[n][i][c] = sum_j Wo'[c][j] * F[n][i][j]
__global__ __launch_bounds__(256) void k2_M(const float* __restrict__ wsc,
                                            float* __restrict__ ws)
{
    const int idx = blockIdx.x * 256 + threadIdx.x;
    if (idx >= NBATCH * QKC * CCH) return;
    const int n = idx / (QKC * CCH);
    const int r = idx % (QKC * CCH);
    const int i = r >> 6, c = r & 63;
    const float* wo = wsc + OFF_WO + c * 64;
    const float* fr = wsc + OFF_F + n * 2048 + i * 64;
    float acc = 0.0f;
#pragma unroll
    for (int j = 0; j < 64; j++) acc += wo[j] * fr[j];
    ws[OFF_MT + idx] = acc;
}

// Pass B (MFMA): contiguous spans, REVERSE global block->span mapping so the
// earliest-running k3 blocks consume the spans k1 touched last (still in L3).
__global__ __launch_bounds__(256) void k3_passB(const float* __restrict__ x,
                                               const float* __restrict__ wsc,
                                               float* __restrict__ out)
{
    __shared__ float qt[4][16 * 36];   // per-wave q̂ transpose buffer (pad 36)

    const int tid = threadIdx.x;
    const int w = tid >> 6;
    const int lane = tid & 63;
    const int ln = lane & 15;
    const int lg = lane >> 4;

    // reverse mapping: block 0 -> (n = NBATCH-1, last span)
    const int n = NBATCH - 1 - (blockIdx.x / BPN_B);
    const int slot = BPN_B - 1 - (blockIdx.x % BPN_B);
    const float* xn = x + (size_t)n * CCH * HW;
    float* on = out + (size_t)n * CCH * HW;

    bf16x8 wqf[2][2];
#pragma unroll
    for (int kk = 0; kk < 2; kk++)
#pragma unroll
        for (int t = 0; t < 2; t++) {
            bf16x8 a;
#pragma unroll
            for (int j = 0; j < 8; j++)
                a[j] = f2bf(wsc[OFF_WQT + (kk * 32 + lg * 8 + j) * 32 + t * 16 + ln]);
            wqf[kk][t] = a;
        }
    bf16x8 wvf[2][4];
#pragma unroll
    for (int kk = 0; kk < 2; kk++)
#pragma unroll
        for (int t = 0; t < 4; t++) {
            bf16x8 a;
#pragma unroll
            for (int j = 0; j < 8; j++)
                a[j] = f2bf(wsc[OFF_WVT + (kk * 32 + lg * 8 + j) * 64 + t * 16 + ln]);
            wvf[kk][t] = a;
        }
    bf16x8 mtf[4];
#pragma unroll
    for (int t = 0; t < 4; t++) {
        bf16x8 a;
#pragma unroll
        for (int j = 0; j < 8; j++)
            a[j] = f2bf(wsc[OFF_MT + n * 2048 + (lg * 8 + j) * 64 + t * 16 + ln]);
        mtf[t] = a;
    }
    float bqb[2], bvb[4], bob[4];
#pragma unroll
    for (int t = 0; t < 2; t++) bqb[t] = wsc[OFF_BQ + t * 16 + ln];
#pragma unroll
    for (int t = 0; t < 4; t++) bvb[t] = wsc[OFF_BV + t * 16 + ln];
#pragma unroll
    for (int t = 0; t < 4; t++) bob[t] = wsc[OFF_BO + t * 16 + ln];

    const int span0 = slot * NIT_B;   // contiguous span; descending span order
                                      // globally via the reversed block map

    float xf[16];
    {
        const int sbase = (span0 + NIT_B - 1) * 64 + w * 16;
#pragma unroll
        for (int kk = 0; kk < 2; kk++) {
            const float* xp = xn + (size_t)(kk * 32 + lg * 8) * HW + sbase + ln;
#pragma unroll
            for (int j = 0; j < 8; j++) xf[kk * 8 + j] = xp[j * HW];
        }
    }

#pragma unroll
    for (int it = 0; it < NIT_B; ++it) {
        const int sbase = (span0 + NIT_B - 1 - it) * 64 + w * 16;

        float xf2[16];
        if (it + 1 < NIT_B) {
            const int sb2 = (span0 + NIT_B - 2 - it) * 64 + w * 16;
#pragma unroll
            for (int kk = 0; kk < 2; kk++) {
                const float* xp = xn + (size_t)(kk * 32 + lg * 8) * HW + sb2 + ln;
#pragma unroll
                for (int j = 0; j < 8; j++) xf2[kk * 8 + j] = xp[j * HW];
            }
        }

        bf16x8 xa[2];
#pragma unroll
        for (int kk = 0; kk < 2; kk++)
#pragma unroll
            for (int j = 0; j < 8; j++) xa[kk][j] = f2bf(xf[kk * 8 + j]);

        f32x4 dq[2], dv0[4];
#pragma unroll
        for (int t = 0; t < 2; t++) dq[t] = (f32x4){bqb[t], bqb[t], bqb[t], bqb[t]};
#pragma unroll
        for (int t = 0; t < 4; t++) dv0[t] = (f32x4){bvb[t], bvb[t], bvb[t], bvb[t]};
#pragma unroll
        for (int kk = 0; kk < 2; kk++) {
#pragma unroll
            for (int t = 0; t < 2; t++) dq[t] = MFMA_P(xa[kk], wqf[kk][t], dq[t]);
#pragma unroll
            for (int t = 0; t < 4; t++) dv0[t] = MFMA_P(xa[kk], wvf[kk][t], dv0[t]);
        }

        float inv[4];
#pragma unroll
        for (int r = 0; r < 4; r++) {
            float s = dq[0][r] * dq[0][r] + dq[1][r] * dq[1][r];
            s += __shfl_xor(s, 1, 64);
            s += __shfl_xor(s, 2, 64);
            s += __shfl_xor(s, 4, 64);
            s += __shfl_xor(s, 8, 64);
            inv[r] = 1.0f / fmaxf(sqrtf(s), 1e-12f);
        }

        // transpose q̂ through the wave-private LDS slab (wave-local ordering)
#pragma unroll
        for (int t = 0; t < 2; t++)
#pragma unroll
            for (int r = 0; r < 4; r++)
                qt[w][(lg * 4 + r) * 36 + t * 16 + ln] = dq[t][r] * inv[r];
        const f32x4 qlo = *(const f32x4*)&qt[w][ln * 36 + lg * 8];
        const f32x4 qhi = *(const f32x4*)&qt[w][ln * 36 + lg * 8 + 4];
        bf16x8 aq;
#pragma unroll
        for (int j = 0; j < 4; j++) { aq[j] = f2bf(qlo[j]); aq[4 + j] = f2bf(qhi[j]); }

        f32x4 dy[4];
#pragma unroll
        for (int t = 0; t < 4; t++) dy[t] = (f32x4){bob[t], bob[t], bob[t], bob[t]};
#pragma unroll
        for (int t = 0; t < 4; t++) dy[t] = MFMA_P(aq, mtf[t], dy[t]);

        // out[och][px] = relu(y) + v0  (nontemporal: don't evict x from L3)
#pragma unroll
        for (int t = 0; t < 4; t++) {
            float* op = on + (size_t)(t * 16 + ln) * HW + sbase + lg * 4;
            f32x4 o4;
#pragma unroll
            for (int r = 0; r < 4; r++)
                o4[r] = fmaxf(dy[t][r], 0.0f) + dv0[t][r];
            __builtin_nontemporal_store(o4, (f32x4*)op);
        }

        if (it + 1 < NIT_B) {
#pragma unroll
            for (int i = 0; i < 16; i++) xf[i] = xf2[i];
        }
    }
}

extern "C" void kernel_launch(void* const* d_in, const int* in_sizes, int n_in,
                              void* d_out, int out_size, void* d_ws, size_t ws_size,
                              hipStream_t stream)
{
    const float* x    = (const float*)d_in[0];
    const float* Wq   = (const float*)d_in[1];
    const float* bq   = (const float*)d_in[2];
    const float* qg   = (const float*)d_in[3];
    const float* qb   = (const float*)d_in[4];
    const float* qm   = (const float*)d_in[5];
    const float* qv   = (const float*)d_in[6];
    const float* Wk   = (const float*)d_in[7];
    const float* bk   = (const float*)d_in[8];
    const float* kg   = (const float*)d_in[9];
    const float* kb   = (const float*)d_in[10];
    const float* km   = (const float*)d_in[11];
    const float* kvar = (const float*)d_in[12];
    const float* Wv   = (const float*)d_in[13];
    const float* bv   = (const float*)d_in[14];
    const float* vg   = (const float*)d_in[15];
    const float* vb   = (const float*)d_in[16];
    const float* vm   = (const float*)d_in[17];
    const float* vvar = (const float*)d_in[18];
    const float* Wo   = (const float*)d_in[19];
    const float* bo   = (const float*)d_in[20];
    const float* og   = (const float*)d_in[21];
    const float* ob   = (const float*)d_in[22];
    const float* om   = (const float*)d_in[23];
    const float* ovar = (const float*)d_in[24];

    float* ws  = (float*)d_ws;
    float* out = (float*)d_out;

    k0_fold<<<177, 256, 0, stream>>>(Wq, bq, qg, qb, qm, qv,
                                     Wk, bk, kg, kb, km, kvar,
                                     Wv, bv, vg, vb, vm, vvar,
                                     Wo, bo, og, ob, om, ovar, ws);

    k1_passA<<<NBATCH * BPN_A, 256, 0, stream>>>(x, (const float*)ws, ws + OFF_F);

    k2_M<<<128, 256, 0, stream>>>((const float*)ws, ws);

    k3_passB<<<NBATCH * BPN_B, 256, 0, stream>>>(x, (const float*)ws, out);
}